// Round 12
// baseline (175.542 us; speedup 1.0000x reference)
//
#include <hip/hip_runtime.h>

#define S_   4096
#define H_   1024
#define NH_  16
#define NT_  64                            // 64-key tiles
#define SCALE_LOG2E 0.18033688011112042f   // (1/8) * log2(e)

typedef __attribute__((ext_vector_type(8)))  short short8;
typedef __attribute__((ext_vector_type(16))) float f32x16;

__device__ __forceinline__ unsigned short f2bf(float x) {
    union { float f; unsigned u; } c; c.f = x;
    unsigned r = c.u + 0x7fffu + ((c.u >> 16) & 1u);   // RNE
    return (unsigned short)(r >> 16);
}
__device__ __forceinline__ unsigned pk2(float a, float b) {
    return (unsigned)f2bf(a) | ((unsigned)f2bf(b) << 16);
}
__device__ __forceinline__ unsigned pkt(float a, float b) {
    union { float f; unsigned u; } ca, cb; ca.f = a; cb.f = b;
    return __builtin_amdgcn_perm(cb.u, ca.u, 0x07060302u);  // [bf(b) : bf(a)]
}

// ---------------------------------------------------------------------------
// Prepass: fragment-major bf16 tile images, 4096 u16 per (hd,kt):
//   K''[kc][key][8] : kc = d>>3   (linear = kc*512 + key*8 + e)
//   V''[kc][d][8]   : kc = key>>3 (linear = kc*512 + d*8 + e)
// LDS transpose staging so BOTH sides are contiguous. (passing, round 5)
// ---------------------------------------------------------------------------
__global__ __launch_bounds__(256) void prepack(
    const float* __restrict__ k, const float* __restrict__ v,
    unsigned short* __restrict__ kp, unsigned short* __restrict__ vtp)
{
    __shared__ unsigned sK[64 * 33];
    __shared__ unsigned sV[64 * 33];

    const int t  = threadIdx.x;
    const int kt = blockIdx.x, hd = blockIdx.y;
    const size_t tb = ((size_t)hd * NT_ + kt) * 4096;
    uint4* gk = (uint4*)(kp + tb);
    uint4* gv = (uint4*)(vtp + tb);

    #pragma unroll
    for (int i = 0; i < 4; ++i) {
        int n   = t + 256 * i;
        int row = n >> 4, c4 = n & 15;
        size_t off = (size_t)(kt * 64 + row) * H_ + hd * 64 + c4 * 4;
        {
            float4 a = *(const float4*)(k + off);
            sK[row * 33 + c4 * 2]     = pk2(a.x, a.y);
            sK[row * 33 + c4 * 2 + 1] = pk2(a.z, a.w);
        }
        {
            float4 a = *(const float4*)(v + off);
            sV[row * 33 + c4 * 2]     = pk2(a.x, a.y);
            sV[row * 33 + c4 * 2 + 1] = pk2(a.z, a.w);
        }
    }
    __syncthreads();

    #pragma unroll
    for (int i = 0; i < 2; ++i) {
        int o = t + 256 * i;
        {   // K''
            int kc = o >> 6, key = o & 63;
            uint4 w;
            w.x = sK[key * 33 + kc * 4];
            w.y = sK[key * 33 + kc * 4 + 1];
            w.z = sK[key * 33 + kc * 4 + 2];
            w.w = sK[key * 33 + kc * 4 + 3];
            gk[o] = w;
        }
        {   // V''
            int kc = o >> 6, d = o & 63;
            int dp = d >> 1, sh = (d & 1) * 16;
            unsigned q[8];
            #pragma unroll
            for (int e = 0; e < 8; ++e)
                q[e] = (sV[(kc * 8 + e) * 33 + dp] >> sh) & 0xffffu;
            uint4 w;
            w.x = q[0] | (q[1] << 16);
            w.y = q[2] | (q[3] << 16);
            w.z = q[4] | (q[5] << 16);
            w.w = q[6] | (q[7] << 16);
            gv[o] = w;
        }
    }
}

// ---------------------------------------------------------------------------
// Main: round-1 structure (proven passing at 104us with 3 blocks/CU), now at
// FULL occupancy: 1024 blocks x 256 threads, __launch_bounds__(256,4) ->
// 4 blocks/CU, 4 waves/SIMD, all blocks resident (no tail). Wave (qh, kh)
// owns 32 qrows x 32-key half; 64 qrows/block. Zero barriers in the K-loop;
// register double-buffer of K+V fragments (68-100 VGPR, well under the
// 128 cap); v_permlane32_swap exchange; loop-invariant zero C-operand.
// 2x the latency-hiding of every 2-wave/SIMD variant (r2-r11) — attacks the
// measured ~3.5x wall-vs-issue gap (serial QK->exp->PV chain per tile).
// ---------------------------------------------------------------------------
__global__ __launch_bounds__(256, 4) void attn_main(
    const float* __restrict__ q,
    const unsigned short* __restrict__ kp,
    const unsigned short* __restrict__ vtp,
    float* __restrict__ out)
{
    __shared__ __align__(16) float sO[2 * 2048];   // kh=1 partials, per qh
    __shared__ float sL[2 * 64];

    const int t   = threadIdx.x;
    const int b   = blockIdx.x;
    // XCD swizzle: 2 heads per XCD (2MB of K''+V'' resident per 4MB L2)
    const int xcd = b & 7;
    const int bi  = b >> 3;                 // 0..127
    const int hd  = xcd * 2 + (bi >> 6);
    const int qt  = bi & 63;                // 64 q-tiles of 64 rows

    const int w    = t >> 6;                // 0..3
    const int lane = t & 63;
    const int l31  = lane & 31;
    const int lhi  = lane >> 5;
    const int qh   = w >> 1;                // 0..1
    const int kh   = w & 1;

    const unsigned short* gK = kp  + (size_t)hd * NT_ * 4096;
    const unsigned short* gV = vtp + (size_t)hd * NT_ * 4096;

    // ---- Q fragments (B-operand), scaled, in registers ----
    short8 qf[4];
    {
        const float* qb = q + (size_t)(qt * 64 + qh * 32 + l31) * H_ + hd * 64 + lhi * 8;
        #pragma unroll
        for (int c = 0; c < 4; ++c) {
            float4 a  = *(const float4*)(qb + c * 16);
            float4 bb = *(const float4*)(qb + c * 16 + 4);
            union { short8 v; unsigned u[4]; } f;
            f.u[0] = pk2(a.x * SCALE_LOG2E, a.y * SCALE_LOG2E);
            f.u[1] = pk2(a.z * SCALE_LOG2E, a.w * SCALE_LOG2E);
            f.u[2] = pk2(bb.x * SCALE_LOG2E, bb.y * SCALE_LOG2E);
            f.u[3] = pk2(bb.z * SCALE_LOG2E, bb.w * SCALE_LOG2E);
            qf[c] = f.v;
        }
    }

    f32x16 Oacc[2];
    #pragma unroll
    for (int h = 0; h < 2; ++h)
        #pragma unroll
        for (int r = 0; r < 16; ++r) Oacc[h][r] = 0.0f;
    float2 ls2; ls2.x = 0.0f; ls2.y = 0.0f;

    // loop-invariant zero C-operand
    f32x16 zero16;
    #pragma unroll
    for (int r = 0; r < 16; ++r) zero16[r] = 0.0f;

    // lane-invariant element offsets into a tile (u16 units)
    const int kOff = (kh * 32 + l31) * 8 + lhi * 512;     // + c*1024
    const int vOff = l31 * 8 + (kh * 4 + lhi) * 512;      // + c*1024 + h*256
    const unsigned short* pK = gK + kOff;
    const unsigned short* pV = gV + vOff;

    short8 kfA[4], vfA[4], kfB[4], vfB[4];

#define LOADF(KF, VF, tile)                                                  \
    {                                                                        \
        const unsigned short* kt_ = pK + (size_t)(tile) * 4096;              \
        const unsigned short* vt_ = pV + (size_t)(tile) * 4096;              \
        KF[0] = *(const short8*)(kt_);                                       \
        KF[1] = *(const short8*)(kt_ + 1024);                                \
        KF[2] = *(const short8*)(kt_ + 2048);                                \
        KF[3] = *(const short8*)(kt_ + 3072);                                \
        VF[0] = *(const short8*)(vt_);                                       \
        VF[1] = *(const short8*)(vt_ + 256);                                 \
        VF[2] = *(const short8*)(vt_ + 1024);                                \
        VF[3] = *(const short8*)(vt_ + 1280);                                \
    }

#define COMPUTE(KF, VF)                                                      \
    {                                                                        \
        f32x16 st = __builtin_amdgcn_mfma_f32_32x32x16_bf16(KF[0], qf[0], zero16, 0, 0, 0); \
        st = __builtin_amdgcn_mfma_f32_32x32x16_bf16(KF[1], qf[1], st, 0, 0, 0); \
        st = __builtin_amdgcn_mfma_f32_32x32x16_bf16(KF[2], qf[2], st, 0, 0, 0); \
        st = __builtin_amdgcn_mfma_f32_32x32x16_bf16(KF[3], qf[3], st, 0, 0, 0); \
        unsigned pu[8];                                                      \
        _Pragma("unroll")                                                    \
        for (int i2_ = 0; i2_ < 8; ++i2_) {                                  \
            float p0 = __builtin_amdgcn_exp2f(st[2 * i2_]);                  \
            float p1 = __builtin_amdgcn_exp2f(st[2 * i2_ + 1]);              \
            ls2.x += p0; ls2.y += p1;                                        \
            pu[i2_] = pkt(p0, p1);                                           \
        }                                                                    \
        _Pragma("unroll")                                                    \
        for (int c_ = 0; c_ < 2; ++c_) {                                     \
            unsigned a0 = pu[4 * c_],     b0 = pu[4 * c_ + 2];               \
            unsigned a1 = pu[4 * c_ + 1], b1 = pu[4 * c_ + 3];               \
            /* a' = {a.lo, b.lo}; b' = {a.hi, b.hi} */                       \
            asm("v_permlane32_swap_b32 %0, %1" : "+v"(a0), "+v"(b0));        \
            asm("v_permlane32_swap_b32 %0, %1" : "+v"(a1), "+v"(b1));        \
            union { short8 v; unsigned u[4]; } pf;                           \
            pf.u[0] = a0; pf.u[1] = a1; pf.u[2] = b0; pf.u[3] = b1;          \
            Oacc[0] = __builtin_amdgcn_mfma_f32_32x32x16_bf16(pf.v, VF[2 * c_],     Oacc[0], 0, 0, 0); \
            Oacc[1] = __builtin_amdgcn_mfma_f32_32x32x16_bf16(pf.v, VF[2 * c_ + 1], Oacc[1], 0, 0, 0); \
        }                                                                    \
    }

    // ---- software-pipelined K-loop: prefetch tile t+1 while computing t ----
    LOADF(kfA, vfA, 0);
    for (int kt2 = 0; kt2 < 31; ++kt2) {
        LOADF(kfB, vfB, 2 * kt2 + 1);
        COMPUTE(kfA, vfA);
        LOADF(kfA, vfA, 2 * kt2 + 2);
        COMPUTE(kfB, vfB);
    }
    LOADF(kfB, vfB, 63);
    COMPUTE(kfA, vfA);
    COMPUTE(kfB, vfB);

#undef LOADF
#undef COMPUTE

    // ---- epilogue: combine kh halves, normalize, store ----
    float lsum = ls2.x + ls2.y;
    lsum += __shfl_xor(lsum, 32);
    if (lhi == 0) sL[kh * 64 + qh * 32 + l31] = lsum;
    if (kh == 1) {
        float* o = sO + qh * 2048;
        #pragma unroll
        for (int h = 0; h < 2; ++h)
            #pragma unroll
            for (int r = 0; r < 16; ++r)
                o[h * 1024 + r * 64 + lane] = Oacc[h][r];
    }
    __syncthreads();
    if (kh == 0) {
        float linv[4][4];
        #pragma unroll
        for (int qd = 0; qd < 4; ++qd) {
            int base = qh * 32 + 8 * qd + 4 * lhi;
            float4 a  = *(const float4*)(sL + base);
            float4 bb = *(const float4*)(sL + 64 + base);
            linv[qd][0] = __builtin_amdgcn_rcpf(a.x + bb.x);
            linv[qd][1] = __builtin_amdgcn_rcpf(a.y + bb.y);
            linv[qd][2] = __builtin_amdgcn_rcpf(a.z + bb.z);
            linv[qd][3] = __builtin_amdgcn_rcpf(a.w + bb.w);
        }
        const float* o = sO + qh * 2048;
        #pragma unroll
        for (int h = 0; h < 2; ++h)
            #pragma unroll
            for (int qd = 0; qd < 4; ++qd)
                #pragma unroll
                for (int e = 0; e < 4; ++e) {
                    int r   = 4 * qd + e;
                    int row = qh * 32 + e + 8 * qd + 4 * lhi;
                    float val = (Oacc[h][r] + o[h * 1024 + r * 64 + lane]) * linv[qd][e];
                    out[(size_t)(qt * 64 + row) * H_ + hd * 64 + h * 32 + l31] = val;
                }
    }
}

extern "C" void kernel_launch(void* const* d_in, const int* in_sizes, int n_in,
                              void* d_out, int out_size, void* d_ws, size_t ws_size,
                              hipStream_t stream) {
    const float* q = (const float*)d_in[0];
    const float* k = (const float*)d_in[1];
    const float* v = (const float*)d_in[2];
    float* out = (float*)d_out;

    unsigned short* kp  = (unsigned short*)d_ws;                 // [0, 8MB)
    unsigned short* vtp = kp + (size_t)NH_ * NT_ * 4096;         // [8MB, 16MB)

    prepack<<<dim3(NT_, NH_), 256, 0, stream>>>(k, v, kp, vtp);
    attn_main<<<dim3(1024), 256, 0, stream>>>(q, kp, vtp, out);
}